// Round 3
// baseline (608.050 us; speedup 1.0000x reference)
//
#include <hip/hip_runtime.h>
#include <hip/hip_bf16.h>
#include <math.h>

#define SS    16
#define NN    1024
#define RR    4
#define CINC  128
#define COUTC 128
#define RP1   5
#define EPSF  1e-7f

typedef __bf16 bf16x8 __attribute__((ext_vector_type(8)));
typedef __bf16 bf16x4 __attribute__((ext_vector_type(4)));
typedef float  f32x4  __attribute__((ext_vector_type(4)));

// Workspace layout:
//   Yt : bf16 [S*4][COUT][N]  (Y_c = X_s @ W_c, b-major)   16 MiB @ 0
//   wT : bf16 [5][COUT][CIN]  (W_c^T, ch4 = theta^T)      160 KiB @ 16 MiB
#define YT_BYTES ((size_t)SS * RR * COUTC * NN * 2)

// ---------------------------------------------------------------------------
// Stage 0: wT[c][b][a] = bf16(weight[a][b][c]), wT[4][b][a] = bf16(theta[a][b])
// grid = 64 blocks x 256 thr; thread handles one (a,b) pair.
// ---------------------------------------------------------------------------
__global__ __launch_bounds__(256) void convert_kernel(
    const float* __restrict__ weight, const float* __restrict__ theta,
    __bf16* __restrict__ wT)
{
    const int idx = blockIdx.x * 256 + threadIdx.x;   // 0..16383
    const int a = idx >> 7, b = idx & 127;
    f32x4 wv = *(const f32x4*)(weight + ((size_t)a * COUTC + b) * RR);
    wT[(0 * COUTC + b) * CINC + a] = (__bf16)wv.x;
    wT[(1 * COUTC + b) * CINC + a] = (__bf16)wv.y;
    wT[(2 * COUTC + b) * CINC + a] = (__bf16)wv.z;
    wT[(3 * COUTC + b) * CINC + a] = (__bf16)wv.w;
    wT[(4 * COUTC + b) * CINC + a] = (__bf16)theta[(size_t)a * COUTC + b];
}

// ---------------------------------------------------------------------------
// Stage 1: Yt[(s*4+c)*128+b][j] = bf16( sum_a x[s][j][a] * wT[c][b][a] )
// x read fp32 straight from global, converted in-register. No LDS, no barrier.
// grid = 16 jt * 4 ch * 16 s = 1024 blocks; bx = (jt*4+ch)*16+s -> XCD = s%8,
// so Yt_s is produced into the same XCD L2 that main_kernel reads it from.
// ---------------------------------------------------------------------------
__global__ __launch_bounds__(256) void prep_kernel(
    const float* __restrict__ x, const __bf16* __restrict__ wT,
    __bf16* __restrict__ Yt)
{
    const int bx = blockIdx.x;
    const int s  = bx & 15;
    const int r  = bx >> 4;          // 0..63
    const int ch = r & 3;
    const int jt = r >> 2;           // 0..15  (64-token tile)

    const int t = threadIdx.x, lane = t & 63, w = t >> 6;
    const int m16 = lane & 15, quad = lane >> 4;

    const float*  xrow = x  + ((size_t)(s * NN) + jt * 64 + w * 16 + m16) * CINC;
    const __bf16* wch  = wT + (size_t)ch * COUTC * CINC;

    f32x4 acc[8];
#pragma unroll
    for (int i = 0; i < 8; ++i) acc[i] = (f32x4){0.f, 0.f, 0.f, 0.f};

#pragma unroll
    for (int k0 = 0; k0 < CINC; k0 += 32) {
        f32x4 xa = *(const f32x4*)(xrow + k0 + quad * 8);
        f32x4 xc = *(const f32x4*)(xrow + k0 + quad * 8 + 4);
        bf16x8 af;
        af[0] = (__bf16)xa.x; af[1] = (__bf16)xa.y; af[2] = (__bf16)xa.z; af[3] = (__bf16)xa.w;
        af[4] = (__bf16)xc.x; af[5] = (__bf16)xc.y; af[6] = (__bf16)xc.z; af[7] = (__bf16)xc.w;
#pragma unroll
        for (int bs = 0; bs < 8; ++bs) {
            const bf16x8 bf = *(const bf16x8*)(wch + (size_t)(bs * 16 + m16) * CINC + k0 + quad * 8);
            acc[bs] = __builtin_amdgcn_mfma_f32_16x16x32_bf16(af, bf, acc[bs], 0, 0, 0);
        }
    }

    const int j0 = jt * 64 + w * 16 + quad * 4;      // token row base (C/D rows)
#pragma unroll
    for (int bs = 0; bs < 8; ++bs) {
        const int b = bs * 16 + m16;
        bf16x4 v; v[0] = (__bf16)acc[bs][0]; v[1] = (__bf16)acc[bs][1];
                  v[2] = (__bf16)acc[bs][2]; v[3] = (__bf16)acc[bs][3];
        *(bf16x4*)(Yt + ((size_t)((s * 4 + ch) * COUTC + b)) * NN + j0) = v;
    }
}

// ---------------------------------------------------------------------------
// Main: out[s,i,b] = tanh( (x@theta)[s,i,b]
//                        + sum_c norm[s,i,c] * sum_j Ar[s,i,j,c]*Y_c[j,b] )
// 16-row i-tiles, 64-j k-steps. grid = 64 itile * 16 s = 1024 blocks
// = exactly 4 blocks/CU (forced via __launch_bounds__(256,4)); bx -> XCD=s%8.
// Per k-step/thread: 5 aligned dwordx4 A loads (4 j x 5 ch), de-interleave,
// bf16-stage to per-c LDS planes, MFMA against global Y B-fragments.
// ---------------------------------------------------------------------------
__global__ __launch_bounds__(256, 4) void main_kernel(
    const float* __restrict__ A, const float* __restrict__ x,
    const __bf16* __restrict__ Yt, const __bf16* __restrict__ wT,
    float* __restrict__ out)
{
    const int bx = blockIdx.x;
    const int s  = bx & 15;
    const int i0 = (bx >> 4) * 16;

    __shared__ __bf16 lA[2][4][16][72];   // [buf][c][i][j(64)+pad]
    __shared__ float  lnorm[4][16];

    const int t = threadIdx.x;
    const int lane = t & 63, w = t >> 6;
    const int m16 = lane & 15, quad = lane >> 4;

    const int irow = t >> 4;              // staging row 0..15
    const int q    = t & 15;              // staging j-group (4 j's x 5 ch = 20 dw)

    const float* Ap = A + ((size_t)(s * NN + i0 + irow) * NN) * RP1 + q * 20;

    // ---- theta term: accz[bs] = (x @ theta) fragment, straight MFMA ----
    f32x4 accz[2];
    accz[0] = (f32x4){0.f, 0.f, 0.f, 0.f};
    accz[1] = (f32x4){0.f, 0.f, 0.f, 0.f};
    {
        const float*  xrow = x  + ((size_t)(s * NN) + i0 + m16) * CINC;
        const __bf16* wth  = wT + (size_t)4 * COUTC * CINC;
#pragma unroll
        for (int k0 = 0; k0 < CINC; k0 += 32) {
            f32x4 xa = *(const f32x4*)(xrow + k0 + quad * 8);
            f32x4 xc = *(const f32x4*)(xrow + k0 + quad * 8 + 4);
            bf16x8 af;
            af[0] = (__bf16)xa.x; af[1] = (__bf16)xa.y; af[2] = (__bf16)xa.z; af[3] = (__bf16)xa.w;
            af[4] = (__bf16)xc.x; af[5] = (__bf16)xc.y; af[6] = (__bf16)xc.z; af[7] = (__bf16)xc.w;
#pragma unroll
            for (int bs = 0; bs < 2; ++bs) {
                const bf16x8 bf = *(const bf16x8*)(wth + (size_t)(w * 32 + bs * 16 + m16) * CINC + k0 + quad * 8);
                accz[bs] = __builtin_amdgcn_mfma_f32_16x16x32_bf16(af, bf, accz[bs], 0, 0, 0);
            }
        }
    }

    float rs[4] = {0.f, 0.f, 0.f, 0.f};
    f32x4 acc[4][2];
#pragma unroll
    for (int c = 0; c < 4; ++c)
#pragma unroll
        for (int bs = 0; bs < 2; ++bs) acc[c][bs] = (f32x4){0.f, 0.f, 0.f, 0.f};

    const __bf16* Ys = Yt + (size_t)s * 4 * COUTC * NN;

    // prologue A prefetch: 5 aligned dwordx4 = 4 j's x 5 channels
    f32x4 ld[5];
#pragma unroll
    for (int u = 0; u < 5; ++u) ld[u] = __builtin_nontemporal_load((const f32x4*)Ap + u);

    for (int kk = 0; kk < 16; ++kk) {
        const int p = kk & 1;

        {   // de-interleave channels, bf16-stage, fp32 row-sum partials
            const float v0[4] = {ld[0].x, ld[1].y, ld[2].z, ld[3].w};
            const float v1[4] = {ld[0].y, ld[1].z, ld[2].w, ld[4].x};
            const float v2[4] = {ld[0].z, ld[1].w, ld[3].x, ld[4].y};
            const float v3[4] = {ld[0].w, ld[2].x, ld[3].y, ld[4].z};
            const float* vv[4] = {v0, v1, v2, v3};
#pragma unroll
            for (int c = 0; c < 4; ++c) {
                const float* v = vv[c];
                rs[c] += v[0] + v[1] + v[2] + v[3];
                bf16x4 pk; pk[0] = (__bf16)v[0]; pk[1] = (__bf16)v[1];
                           pk[2] = (__bf16)v[2]; pk[3] = (__bf16)v[3];
                *(bf16x4*)&lA[p][c][irow][q * 4] = pk;
            }
        }
        __syncthreads();

        if (kk < 15) {     // next A step in flight across this step's MFMAs
            Ap += 320;
#pragma unroll
            for (int u = 0; u < 5; ++u) ld[u] = __builtin_nontemporal_load((const f32x4*)Ap + u);
        }

#pragma unroll
        for (int c = 0; c < 4; ++c) {
            const __bf16* yp = Ys + (size_t)(c * COUTC + w * 32 + m16) * NN + kk * 64 + quad * 8;
#pragma unroll
            for (int ks = 0; ks < 2; ++ks) {
                const bf16x8 af = *(const bf16x8*)&lA[p][c][m16][ks * 32 + quad * 8];
                const bf16x8 b0 = *(const bf16x8*)(yp + ks * 32);
                const bf16x8 b1 = *(const bf16x8*)(yp + (size_t)16 * NN + ks * 32);
                acc[c][0] = __builtin_amdgcn_mfma_f32_16x16x32_bf16(af, b0, acc[c][0], 0, 0, 0);
                acc[c][1] = __builtin_amdgcn_mfma_f32_16x16x32_bf16(af, b1, acc[c][1], 0, 0, 0);
            }
        }
    }

    // row-sums -> norms (16 staging lanes per row, xor-shuffle reduce over q)
#pragma unroll
    for (int c = 0; c < 4; ++c) {
        float v = rs[c];
        v += __shfl_xor(v, 1);
        v += __shfl_xor(v, 2);
        v += __shfl_xor(v, 4);
        v += __shfl_xor(v, 8);
        if (q == 0) lnorm[c][irow] = 1.0f / (v + EPSF);
    }
    __syncthreads();

    // epilogue: combine c's with norms, add theta term, tanh, store
    {
        f32x4 nv[4];
#pragma unroll
        for (int c = 0; c < 4; ++c) nv[c] = *(const f32x4*)&lnorm[c][quad * 4];
        const int row0 = i0 + quad * 4;
#pragma unroll
        for (int bs = 0; bs < 2; ++bs) {
            const int b = w * 32 + bs * 16 + m16;
#pragma unroll
            for (int r = 0; r < 4; ++r) {
                float v = acc[0][bs][r] * nv[0][r]
                        + acc[1][bs][r] * nv[1][r]
                        + acc[2][bs][r] * nv[2][r]
                        + acc[3][bs][r] * nv[3][r]
                        + accz[bs][r];
                out[((size_t)s * NN + row0 + r) * COUTC + b] = tanhf(v);
            }
        }
    }
}

extern "C" void kernel_launch(void* const* d_in, const int* in_sizes, int n_in,
                              void* d_out, int out_size, void* d_ws, size_t ws_size,
                              hipStream_t stream)
{
    const float* A      = (const float*)d_in[0];
    const float* x      = (const float*)d_in[1];
    const float* weight = (const float*)d_in[2];
    const float* theta  = (const float*)d_in[3];
    float* out = (float*)d_out;

    __bf16* Yt = (__bf16*)d_ws;
    __bf16* wT = (__bf16*)((char*)d_ws + YT_BYTES);

    convert_kernel<<<dim3(64), dim3(256), 0, stream>>>(weight, theta, wT);
    prep_kernel<<<dim3(SS * RR * 16), dim3(256), 0, stream>>>(x, wT, Yt);
    main_kernel<<<dim3(SS * 64), dim3(256), 0, stream>>>(A, x, Yt, wT, out);
}